// Round 2
// baseline (3030.967 us; speedup 1.0000x reference)
//
#include <hip/hip_runtime.h>
#include <hip/hip_bf16.h>

typedef __bf16 bf16_t;
typedef __bf16 bf16x8 __attribute__((ext_vector_type(8)));
typedef float  f32x4  __attribute__((ext_vector_type(4)));
typedef float  f32x8  __attribute__((ext_vector_type(8)));

constexpr int T_ = 2048, H_ = 2048, I_ = 5632, E_ = 8, S_ = T_ * 2;

// ---- workspace layout (bytes) ----  total ~88.2 MB
constexpr size_t OFF_HB    = 0;                                   // bf16 hidden  [T][H]
constexpr size_t OFF_HOUT  = OFF_HB    + (size_t)T_ * H_ * 2;     // bf16 h       [S][I]
constexpr size_t OFF_DPART = OFF_HOUT  + (size_t)S_ * I_ * 2;     // f32 downpart [S][H]
constexpr size_t OFF_TOS   = OFF_DPART + (size_t)S_ * H_ * 4;     // int token_of_slot[S]
constexpr size_t OFF_SOT   = OFF_TOS   + (size_t)S_ * 4;          // int slot_of_tk[T*2]
constexpr size_t OFF_TKI   = OFF_SOT   + (size_t)S_ * 4;          // int topk_idx[T*2]
constexpr size_t OFF_TKW   = OFF_TKI   + (size_t)S_ * 4;          // f32 topk_w[T*2]
constexpr size_t OFF_CNT   = OFF_TKW   + (size_t)S_ * 4;          // int counts[E]
constexpr size_t OFF_OFFS  = OFF_CNT   + 64;                      // int offs[E]
constexpr size_t OFF_CUR   = OFF_OFFS  + 64;                      // int cursor[E]

// async global->LDS, 16B per lane. LDS dest = wave-uniform base + lane*16 (HW).
__device__ __forceinline__ void gload16(const void* g, void* l) {
  __builtin_amdgcn_global_load_lds(
      (const __attribute__((address_space(1))) void*)g,
      (__attribute__((address_space(3))) void*)l, 16, 0, 0);
}

// ================= router: logits, softmax, top-2, bf16 convert =================
__global__ __launch_bounds__(256)
void router_kernel(const float* __restrict__ hs, const float* __restrict__ gw,
                   int* __restrict__ tki, float* __restrict__ tkw,
                   int* __restrict__ counts, bf16_t* __restrict__ hb)
{
  const int t = blockIdx.x;
  const int tid = threadIdx.x;
  const int lane = tid & 63, wid = tid >> 6;
  const float* hrow = hs + (size_t)t * H_;
  const int c0 = tid * 8;
  float4 h0 = *(const float4*)(hrow + c0);
  float4 h1 = *(const float4*)(hrow + c0 + 4);
  bf16x8 hv;
  hv[0]=(bf16_t)h0.x; hv[1]=(bf16_t)h0.y; hv[2]=(bf16_t)h0.z; hv[3]=(bf16_t)h0.w;
  hv[4]=(bf16_t)h1.x; hv[5]=(bf16_t)h1.y; hv[6]=(bf16_t)h1.z; hv[7]=(bf16_t)h1.w;
  *(bf16x8*)(hb + (size_t)t * H_ + c0) = hv;

  float acc[E_];
  #pragma unroll
  for (int e = 0; e < E_; ++e) {
    const float* g = gw + (size_t)e * H_ + c0;
    float4 g0 = *(const float4*)(g);
    float4 g1 = *(const float4*)(g + 4);
    acc[e] = h0.x*g0.x + h0.y*g0.y + h0.z*g0.z + h0.w*g0.w
           + h1.x*g1.x + h1.y*g1.y + h1.z*g1.z + h1.w*g1.w;
  }
  #pragma unroll
  for (int e = 0; e < E_; ++e)
    #pragma unroll
    for (int o = 32; o > 0; o >>= 1)
      acc[e] += __shfl_down(acc[e], o);
  __shared__ float red[4][E_];
  if (lane == 0)
    #pragma unroll
    for (int e = 0; e < E_; ++e) red[wid][e] = acc[e];
  __syncthreads();
  if (tid == 0) {
    float l[E_];
    #pragma unroll
    for (int e = 0; e < E_; ++e) l[e] = red[0][e] + red[1][e] + red[2][e] + red[3][e];
    float m = l[0];
    #pragma unroll
    for (int e = 1; e < E_; ++e) m = fmaxf(m, l[e]);
    float p[E_]; float s = 0.f;
    #pragma unroll
    for (int e = 0; e < E_; ++e) { p[e] = __expf(l[e] - m); s += p[e]; }
    int i1 = 0;
    #pragma unroll
    for (int e = 1; e < E_; ++e) if (l[e] > l[i1]) i1 = e;
    int i2 = (i1 == 0) ? 1 : 0;
    #pragma unroll
    for (int e = 0; e < E_; ++e) if (e != i1 && l[e] > l[i2]) i2 = e;
    tki[2*t] = i1; tki[2*t+1] = i2;
    tkw[2*t] = p[i1] / s; tkw[2*t+1] = p[i2] / s;
    atomicAdd(&counts[i1], 1);
    atomicAdd(&counts[i2], 1);
  }
}

// ================= scan: expert offsets + slot lists =================
__global__ void scan_kernel(const int* __restrict__ counts, const int* __restrict__ tki,
                            int* __restrict__ offs, int* __restrict__ cursor,
                            int* __restrict__ tos, int* __restrict__ sot)
{
  if (threadIdx.x == 0) {
    int run = 0;
    for (int e = 0; e < E_; ++e) { offs[e] = run; cursor[e] = run; run += counts[e]; }
  }
  __syncthreads();
  for (int t = threadIdx.x; t < T_; t += blockDim.x) {
    #pragma unroll
    for (int k = 0; k < 2; ++k) {
      int e = tki[2*t + k];
      int s = atomicAdd(&cursor[e], 1);
      tos[s] = t;
      sot[2*t + k] = s;
    }
  }
}

// ================= GEMM1: gathered hidden x w1^T, dual (gate,up) acc, fused silu*mul =================
// m97-style: single-buffer LDS, global_load_lds staging, 2 barriers/K-step.
// A bf16 in LDS; B kept f32 in LDS, converted to bf16 at fragment-read time.
constexpr int G1_BM = 128, G1_BN = 64, G1_BK = 64;

__global__ __launch_bounds__(256)
void gemm1_kernel(const bf16_t* __restrict__ hb, const float* __restrict__ w1,
                  const int* __restrict__ tos, const int* __restrict__ offs,
                  const int* __restrict__ counts, bf16_t* __restrict__ hout)
{
  const int e = blockIdx.z;
  const int cnt = counts[e];
  const int m0 = blockIdx.x * G1_BM;     // m innermost: m-tiles of same (n,e) concurrent -> L2 reuse of B strip
  if (m0 >= cnt) return;
  const int off = offs[e];
  const int n0 = blockIdx.y * G1_BN;

  const float* Wg = w1 + (size_t)e * (2 * (size_t)I_ * H_) + (size_t)n0 * H_;
  const float* Wu = Wg + (size_t)I_ * H_;

  __shared__ bf16_t Al[G1_BM][G1_BK];    // 16 KB
  __shared__ float  Bgl[G1_BN][G1_BK];   // 16 KB
  __shared__ float  Bul[G1_BN][G1_BK];   // 16 KB

  const int tid = threadIdx.x;
  const int lane = tid & 63, wid = tid >> 6;
  const int wm = wid >> 1, wn = wid & 1;
  const int l15 = lane & 15, l4 = lane >> 4;

  // A: 16 chunks of 1KB (8 rows x 64 bf16 each); wave w stages chunks w*4+i.
  // within chunk: lane offset lane*16 = (lane>>3)*128 + (lane&7)*16 -> row q*8+(lane>>3), col (lane&7)*8
  const bf16_t* agp[4]; char* alds[4];
  #pragma unroll
  for (int i = 0; i < 4; ++i) {
    int q = wid * 4 + i;
    int row = q * 8 + (lane >> 3);
    int slot = off + m0 + row, mx = off + cnt - 1;
    if (slot > mx) slot = mx;            // clamp pad rows (dup loads, results masked at store)
    agp[i]  = hb + (size_t)tos[slot] * H_ + (lane & 7) * 8;
    alds[i] = (char*)&Al[0][0] + q * 1024;
  }
  // B (f32): 16 chunks of 1KB (4 rows x 64 f32); lane*16 = (lane>>4)*256 + (lane&15)*16
  const float* bgp[4]; const float* bup[4]; char* bglds[4]; char* bulds[4];
  #pragma unroll
  for (int i = 0; i < 4; ++i) {
    int q = wid * 4 + i;
    int row = q * 4 + (lane >> 4);
    bgp[i]   = Wg + (size_t)row * H_ + (lane & 15) * 4;
    bup[i]   = Wu + (size_t)row * H_ + (lane & 15) * 4;
    bglds[i] = (char*)&Bgl[0][0] + q * 1024;
    bulds[i] = (char*)&Bul[0][0] + q * 1024;
  }

  auto stage = [&](int k0) {
    #pragma unroll
    for (int i = 0; i < 4; ++i) gload16(agp[i] + k0, alds[i]);
    #pragma unroll
    for (int i = 0; i < 4; ++i) gload16(bgp[i] + k0, bglds[i]);
    #pragma unroll
    for (int i = 0; i < 4; ++i) gload16(bup[i] + k0, bulds[i]);
  };

  f32x4 accg[4][2], accu[4][2];
  #pragma unroll
  for (int mi = 0; mi < 4; ++mi)
    #pragma unroll
    for (int ni = 0; ni < 2; ++ni) {
      accg[mi][ni] = f32x4{0.f,0.f,0.f,0.f};
      accu[mi][ni] = f32x4{0.f,0.f,0.f,0.f};
    }

  constexpr int NK = H_ / G1_BK;   // 32
  stage(0);
  for (int kt = 0; kt < NK; ++kt) {
    __syncthreads();               // compiler drains vmcnt(0) before barrier -> tile ready
    #pragma unroll
    for (int ks = 0; ks < 2; ++ks) {
      const int kb = ks * 32 + l4 * 8;
      bf16x8 af[4];
      #pragma unroll
      for (int mi = 0; mi < 4; ++mi) af[mi] = *(const bf16x8*)&Al[wm*64 + mi*16 + l15][kb];
      bf16x8 bgf[2], buf2[2];
      #pragma unroll
      for (int ni = 0; ni < 2; ++ni) {
        f32x8 tg = *(const f32x8*)&Bgl[wn*32 + ni*16 + l15][kb];
        f32x8 tu = *(const f32x8*)&Bul[wn*32 + ni*16 + l15][kb];
        #pragma unroll
        for (int j = 0; j < 8; ++j) { bgf[ni][j] = (bf16_t)tg[j]; buf2[ni][j] = (bf16_t)tu[j]; }
      }
      #pragma unroll
      for (int mi = 0; mi < 4; ++mi)
        #pragma unroll
        for (int ni = 0; ni < 2; ++ni) {
          accg[mi][ni] = __builtin_amdgcn_mfma_f32_16x16x32_bf16(af[mi], bgf[ni],  accg[mi][ni], 0, 0, 0);
          accu[mi][ni] = __builtin_amdgcn_mfma_f32_16x16x32_bf16(af[mi], buf2[ni], accu[mi][ni], 0, 0, 0);
        }
    }
    __syncthreads();               // all waves done reading before overwrite
    if (kt + 1 < NK) stage((kt + 1) * G1_BK);
  }

  // epilogue: silu(g)*u -> bf16 h[slot][i]   (C/D map: row=(lane>>4)*4+j, col=lane&15 — verified r1)
  #pragma unroll
  for (int mi = 0; mi < 4; ++mi)
    #pragma unroll
    for (int ni = 0; ni < 2; ++ni)
      #pragma unroll
      for (int j = 0; j < 4; ++j) {
        int rel = wm*64 + mi*16 + l4*4 + j;
        if (m0 + rel < cnt) {
          int col = n0 + wn*32 + ni*16 + l15;
          float g = accg[mi][ni][j];
          float u = accu[mi][ni][j];
          float hvv = (g / (1.0f + __expf(-g))) * u;
          hout[(size_t)(off + m0 + rel) * I_ + col] = (bf16_t)hvv;
        }
      }
}

// ================= GEMM2: h x w2^T -> per-slot partial (f32) =================
constexpr int G2_BM = 128, G2_BN = 128, G2_BK = 64;

__global__ __launch_bounds__(256)
void gemm2_kernel(const bf16_t* __restrict__ hbuf, const float* __restrict__ w2,
                  const int* __restrict__ offs, const int* __restrict__ counts,
                  float* __restrict__ dpart)
{
  const int e = blockIdx.z;
  const int cnt = counts[e];
  const int m0 = blockIdx.x * G2_BM;
  if (m0 >= cnt) return;
  const int off = offs[e];
  const int n0 = blockIdx.y * G2_BN;
  const float* W = w2 + (size_t)e * ((size_t)H_ * I_) + (size_t)n0 * I_;

  __shared__ bf16_t Al[G2_BM][G2_BK];   // 16 KB
  __shared__ float  Bl[G2_BN][G2_BK];   // 32 KB

  const int tid = threadIdx.x;
  const int lane = tid & 63, wid = tid >> 6;
  const int wm = wid >> 1, wn = wid & 1;
  const int l15 = lane & 15, l4 = lane >> 4;

  const bf16_t* agp[4]; char* alds[4];
  #pragma unroll
  for (int i = 0; i < 4; ++i) {
    int q = wid * 4 + i;
    int row = q * 8 + (lane >> 3);
    int slot = off + m0 + row, mx = off + cnt - 1;
    if (slot > mx) slot = mx;
    agp[i]  = hbuf + (size_t)slot * I_ + (lane & 7) * 8;
    alds[i] = (char*)&Al[0][0] + q * 1024;
  }
  // B: 32 chunks of 1KB (4 rows x 64 f32); wave w stages chunks w*8+i
  const float* bp[8]; char* blds[8];
  #pragma unroll
  for (int i = 0; i < 8; ++i) {
    int q = wid * 8 + i;
    int row = q * 4 + (lane >> 4);
    bp[i]   = W + (size_t)row * I_ + (lane & 15) * 4;
    blds[i] = (char*)&Bl[0][0] + q * 1024;
  }

  auto stage = [&](int k0) {
    #pragma unroll
    for (int i = 0; i < 4; ++i) gload16(agp[i] + k0, alds[i]);
    #pragma unroll
    for (int i = 0; i < 8; ++i) gload16(bp[i] + k0, blds[i]);
  };

  f32x4 acc[4][4];
  #pragma unroll
  for (int mi = 0; mi < 4; ++mi)
    #pragma unroll
    for (int ni = 0; ni < 4; ++ni) acc[mi][ni] = f32x4{0.f,0.f,0.f,0.f};

  constexpr int NK = I_ / G2_BK;   // 88
  stage(0);
  for (int kt = 0; kt < NK; ++kt) {
    __syncthreads();
    #pragma unroll
    for (int ks = 0; ks < 2; ++ks) {
      const int kb = ks * 32 + l4 * 8;
      bf16x8 af[4];
      #pragma unroll
      for (int mi = 0; mi < 4; ++mi) af[mi] = *(const bf16x8*)&Al[wm*64 + mi*16 + l15][kb];
      bf16x8 bf[4];
      #pragma unroll
      for (int ni = 0; ni < 4; ++ni) {
        f32x8 tb = *(const f32x8*)&Bl[wn*64 + ni*16 + l15][kb];
        #pragma unroll
        for (int j = 0; j < 8; ++j) bf[ni][j] = (bf16_t)tb[j];
      }
      #pragma unroll
      for (int mi = 0; mi < 4; ++mi)
        #pragma unroll
        for (int ni = 0; ni < 4; ++ni)
          acc[mi][ni] = __builtin_amdgcn_mfma_f32_16x16x32_bf16(af[mi], bf[ni], acc[mi][ni], 0, 0, 0);
    }
    __syncthreads();
    if (kt + 1 < NK) stage((kt + 1) * G2_BK);
  }

  #pragma unroll
  for (int mi = 0; mi < 4; ++mi)
    #pragma unroll
    for (int ni = 0; ni < 4; ++ni)
      #pragma unroll
      for (int j = 0; j < 4; ++j) {
        int rel = wm*64 + mi*16 + l4*4 + j;
        if (m0 + rel < cnt) {
          int col = n0 + wn*64 + ni*16 + l15;
          dpart[(size_t)(off + m0 + rel) * H_ + col] = acc[mi][ni][j];
        }
      }
}

// ================= combine: out[t] = w0*d[s0] + w1*d[s1] =================
__global__ __launch_bounds__(256)
void combine_kernel(const float* __restrict__ dpart, const int* __restrict__ sot,
                    const float* __restrict__ tkw, float* __restrict__ out)
{
  int idx = blockIdx.x * 256 + threadIdx.x;     // T*H/4 total
  int t = idx >> 9;                              // H/4 = 512
  int c = (idx & 511) * 4;
  float wA = tkw[2*t], wB = tkw[2*t+1];
  int sA = sot[2*t], sB = sot[2*t+1];
  float4 a = *(const float4*)(dpart + (size_t)sA * H_ + c);
  float4 b = *(const float4*)(dpart + (size_t)sB * H_ + c);
  float4 o;
  o.x = wA*a.x + wB*b.x; o.y = wA*a.y + wB*b.y;
  o.z = wA*a.z + wB*b.z; o.w = wA*a.w + wB*b.w;
  *(float4*)(out + (size_t)t * H_ + c) = o;
}

extern "C" void kernel_launch(void* const* d_in, const int* in_sizes, int n_in,
                              void* d_out, int out_size, void* d_ws, size_t ws_size,
                              hipStream_t stream) {
  const float* hs = (const float*)d_in[0];
  const float* gw = (const float*)d_in[1];
  const float* w1 = (const float*)d_in[2];
  const float* w2 = (const float*)d_in[3];
  float* out = (float*)d_out;
  char* ws = (char*)d_ws;

  bf16_t* hb    = (bf16_t*)(ws + OFF_HB);
  bf16_t* hout  = (bf16_t*)(ws + OFF_HOUT);
  float*  dpart = (float*) (ws + OFF_DPART);
  int*    tos   = (int*)   (ws + OFF_TOS);
  int*    sot   = (int*)   (ws + OFF_SOT);
  int*    tki   = (int*)   (ws + OFF_TKI);
  float*  tkw   = (float*) (ws + OFF_TKW);
  int*    cnt   = (int*)   (ws + OFF_CNT);
  int*    offp  = (int*)   (ws + OFF_OFFS);
  int*    curp  = (int*)   (ws + OFF_CUR);

  hipMemsetAsync(ws + OFF_CNT, 0, 64, stream);   // zero expert counts each call

  router_kernel<<<T_, 256, 0, stream>>>(hs, gw, tki, tkw, cnt, hb);
  scan_kernel<<<1, 256, 0, stream>>>(cnt, tki, offp, curp, tos, sot);
  gemm1_kernel<<<dim3(T_ / G1_BM, I_ / G1_BN, E_), 256, 0, stream>>>(hb, w1, tos, offp, cnt, hout);
  gemm2_kernel<<<dim3(T_ / G2_BM, H_ / G2_BN, E_), 256, 0, stream>>>(hout, w2, offp, cnt, dpart);
  combine_kernel<<<(T_ * H_ / 4) / 256, 256, 0, stream>>>(dpart, sot, tkw, out);
}

// Round 3
// 1032.902 us; speedup vs baseline: 2.9344x; 2.9344x over previous
//
#include <hip/hip_runtime.h>
#include <hip/hip_bf16.h>

typedef __bf16 bf16_t;
typedef __bf16 bf16x4 __attribute__((ext_vector_type(4)));
typedef __bf16 bf16x8 __attribute__((ext_vector_type(8)));
typedef float  f32x4  __attribute__((ext_vector_type(4)));

constexpr int T_ = 2048, H_ = 2048, I_ = 5632, E_ = 8, S_ = T_ * 2;

// ---- workspace layout (bytes) ----  total ~88.2 MB
constexpr size_t OFF_HB    = 0;                                   // bf16 hidden  [T][H]
constexpr size_t OFF_HOUT  = OFF_HB    + (size_t)T_ * H_ * 2;     // bf16 h       [S][I]
constexpr size_t OFF_DPART = OFF_HOUT  + (size_t)S_ * I_ * 2;     // f32 downpart [S][H]
constexpr size_t OFF_TOS   = OFF_DPART + (size_t)S_ * H_ * 4;     // int token_of_slot[S]
constexpr size_t OFF_SOT   = OFF_TOS   + (size_t)S_ * 4;          // int slot_of_tk[T*2]
constexpr size_t OFF_TKI   = OFF_SOT   + (size_t)S_ * 4;          // int topk_idx[T*2]
constexpr size_t OFF_TKW   = OFF_TKI   + (size_t)S_ * 4;          // f32 topk_w[T*2]
constexpr size_t OFF_CNT   = OFF_TKW   + (size_t)S_ * 4;          // int counts[E]
constexpr size_t OFF_OFFS  = OFF_CNT   + 64;                      // int offs[E]
constexpr size_t OFF_CUR   = OFF_OFFS  + 64;                      // int cursor[E]

// async global->LDS, 16B per lane. LDS dest = wave-uniform base + lane*16 (HW).
__device__ __forceinline__ void gload16(const void* g, void* l) {
  __builtin_amdgcn_global_load_lds(
      (const __attribute__((address_space(1))) void*)g,
      (__attribute__((address_space(3))) void*)l, 16, 0, 0);
}

__device__ __forceinline__ bf16x4 cvt4(const float4 v) {
  bf16x4 r; r[0]=(bf16_t)v.x; r[1]=(bf16_t)v.y; r[2]=(bf16_t)v.z; r[3]=(bf16_t)v.w;
  return r;
}

// ================= router: logits, softmax, top-2, bf16 convert =================
__global__ __launch_bounds__(256)
void router_kernel(const float* __restrict__ hs, const float* __restrict__ gw,
                   int* __restrict__ tki, float* __restrict__ tkw,
                   int* __restrict__ counts, bf16_t* __restrict__ hb)
{
  const int t = blockIdx.x;
  const int tid = threadIdx.x;
  const int lane = tid & 63, wid = tid >> 6;
  const float* hrow = hs + (size_t)t * H_;
  const int c0 = tid * 8;
  float4 h0 = *(const float4*)(hrow + c0);
  float4 h1 = *(const float4*)(hrow + c0 + 4);
  bf16x8 hv;
  hv[0]=(bf16_t)h0.x; hv[1]=(bf16_t)h0.y; hv[2]=(bf16_t)h0.z; hv[3]=(bf16_t)h0.w;
  hv[4]=(bf16_t)h1.x; hv[5]=(bf16_t)h1.y; hv[6]=(bf16_t)h1.z; hv[7]=(bf16_t)h1.w;
  *(bf16x8*)(hb + (size_t)t * H_ + c0) = hv;

  float acc[E_];
  #pragma unroll
  for (int e = 0; e < E_; ++e) {
    const float* g = gw + (size_t)e * H_ + c0;
    float4 g0 = *(const float4*)(g);
    float4 g1 = *(const float4*)(g + 4);
    acc[e] = h0.x*g0.x + h0.y*g0.y + h0.z*g0.z + h0.w*g0.w
           + h1.x*g1.x + h1.y*g1.y + h1.z*g1.z + h1.w*g1.w;
  }
  #pragma unroll
  for (int e = 0; e < E_; ++e)
    #pragma unroll
    for (int o = 32; o > 0; o >>= 1)
      acc[e] += __shfl_down(acc[e], o);
  __shared__ float red[4][E_];
  if (lane == 0)
    #pragma unroll
    for (int e = 0; e < E_; ++e) red[wid][e] = acc[e];
  __syncthreads();
  if (tid == 0) {
    float l[E_];
    #pragma unroll
    for (int e = 0; e < E_; ++e) l[e] = red[0][e] + red[1][e] + red[2][e] + red[3][e];
    float m = l[0];
    #pragma unroll
    for (int e = 1; e < E_; ++e) m = fmaxf(m, l[e]);
    float p[E_]; float s = 0.f;
    #pragma unroll
    for (int e = 0; e < E_; ++e) { p[e] = __expf(l[e] - m); s += p[e]; }
    int i1 = 0;
    #pragma unroll
    for (int e = 1; e < E_; ++e) if (l[e] > l[i1]) i1 = e;
    int i2 = (i1 == 0) ? 1 : 0;
    #pragma unroll
    for (int e = 0; e < E_; ++e) if (e != i1 && l[e] > l[i2]) i2 = e;
    tki[2*t] = i1; tki[2*t+1] = i2;
    tkw[2*t] = p[i1] / s; tkw[2*t+1] = p[i2] / s;
    atomicAdd(&counts[i1], 1);
    atomicAdd(&counts[i2], 1);
  }
}

// ================= scan: expert offsets + slot lists =================
__global__ void scan_kernel(const int* __restrict__ counts, const int* __restrict__ tki,
                            int* __restrict__ offs, int* __restrict__ cursor,
                            int* __restrict__ tos, int* __restrict__ sot)
{
  if (threadIdx.x == 0) {
    int run = 0;
    for (int e = 0; e < E_; ++e) { offs[e] = run; cursor[e] = run; run += counts[e]; }
  }
  __syncthreads();
  for (int t = threadIdx.x; t < T_; t += blockDim.x) {
    #pragma unroll
    for (int k = 0; k < 2; ++k) {
      int e = tki[2*t + k];
      int s = atomicAdd(&cursor[e], 1);
      tos[s] = t;
      sot[2*t + k] = s;
    }
  }
}

// ================= GEMM1: gathered hidden x w1^T, dual (gate,up), fused silu*mul =================
// 2-phase dbuf: stage(k+1) issued BEFORE compute(k); one barrier per K-step.
// A: global_load_lds with pre-swizzled source cols. B: reg-staged f32 -> bf16 ds_write (swizzled).
// Swizzle invariant (all tiles, rows of 128B): LDS(r, byte b) = tile(r, b ^ ((r&7)<<4)).
constexpr int G1_BM = 128, G1_BN = 64, G1_BK = 64;

__global__ __launch_bounds__(256, 2)
void gemm1_kernel(const bf16_t* __restrict__ hb, const float* __restrict__ w1,
                  const int* __restrict__ tos, const int* __restrict__ offs,
                  const int* __restrict__ counts, bf16_t* __restrict__ hout)
{
  // XCD-chunked raster: expert e pinned to XCD (bid&7); m-tiles innermost for L2 strip reuse.
  const int bid = blockIdx.x;
  const int e   = bid & 7;
  const int idx = bid >> 3;          // 0..1407 = 16 m-tiles x 88 n-tiles
  const int mt  = idx & 15;
  const int nt  = idx >> 4;

  const int cnt = counts[e];
  const int m0 = mt * G1_BM;
  if (m0 >= cnt) return;
  const int off = offs[e];
  const int n0 = nt * G1_BN;

  const float* Wg = w1 + (size_t)e * (2 * (size_t)I_ * H_) + (size_t)n0 * H_;
  const float* Wu = Wg + (size_t)I_ * H_;

  __shared__ bf16_t Al [2][G1_BM][G1_BK];   // 32 KB
  __shared__ bf16_t Bgl[2][G1_BN][G1_BK];   // 16 KB
  __shared__ bf16_t Bul[2][G1_BN][G1_BK];   // 16 KB

  const int tid = threadIdx.x;
  const int lane = tid & 63, wid = tid >> 6;
  const int wm = wid >> 1, wn = wid & 1;
  const int l15 = lane & 15, l4 = lane >> 4;

  // --- A staging (global_load_lds): chunk q = 8 rows x 64 cols bf16 = 1KB, lane covers (l>>3, (l&7)*16B)
  // source col pre-swizzled so that linear LDS == swizzled tile.
  const bf16_t* agp[4]; int aoff[4];
  #pragma unroll
  for (int i = 0; i < 4; ++i) {
    int q = wid * 4 + i;
    int row = q * 8 + (lane >> 3);
    int slot = off + m0 + row, mx = off + cnt - 1;
    if (slot > mx) slot = mx;            // clamp pad rows (masked at store)
    agp[i]  = hb + (size_t)tos[slot] * H_ + ((lane & 7) ^ (lane >> 3)) * 8;
    aoff[i] = q * 1024;
  }
  // --- B staging (reg path): thread covers row=tid>>2, 16 f32 at cols 4*(tid&3)+16i (lane-contiguous loads)
  const int brow = tid >> 2, bq = tid & 3;
  const float* gsrc = Wg + (size_t)brow * H_;
  const float* usrc = Wu + (size_t)brow * H_;
  int wby[4];
  #pragma unroll
  for (int i = 0; i < 4; ++i)
    wby[i] = brow * 128 + ((8 * bq + 32 * i) ^ ((brow & 7) << 4));

  float4 bgr[4], bur[4];
  auto loadB = [&](int k0) {
    #pragma unroll
    for (int i = 0; i < 4; ++i) bgr[i] = *(const float4*)(gsrc + k0 + 4 * bq + 16 * i);
    #pragma unroll
    for (int i = 0; i < 4; ++i) bur[i] = *(const float4*)(usrc + k0 + 4 * bq + 16 * i);
  };
  auto stageA = [&](int b, int k0) {
    char* base = (char*)&Al[b][0][0];
    #pragma unroll
    for (int i = 0; i < 4; ++i) gload16(agp[i] + k0, base + aoff[i]);
  };
  auto writeB = [&](int b) {
    char* gb = (char*)&Bgl[b][0][0];
    char* ub = (char*)&Bul[b][0][0];
    #pragma unroll
    for (int i = 0; i < 4; ++i) {
      *(bf16x4*)(gb + wby[i]) = cvt4(bgr[i]);
      *(bf16x4*)(ub + wby[i]) = cvt4(bur[i]);
    }
  };

  f32x4 accg[4][2], accu[4][2];
  #pragma unroll
  for (int mi = 0; mi < 4; ++mi)
    #pragma unroll
    for (int ni = 0; ni < 2; ++ni) {
      accg[mi][ni] = f32x4{0.f,0.f,0.f,0.f};
      accu[mi][ni] = f32x4{0.f,0.f,0.f,0.f};
    }

  auto compute = [&](int b) {
    const char* ab = (const char*)&Al[b][0][0];
    const char* gb = (const char*)&Bgl[b][0][0];
    const char* ub = (const char*)&Bul[b][0][0];
    #pragma unroll
    for (int ks = 0; ks < 2; ++ks) {
      const int cb = ks * 64 + l4 * 16;          // byte col base (pre-swizzle)
      bf16x8 af[4], bgf[2], buf2[2];
      #pragma unroll
      for (int mi = 0; mi < 4; ++mi) {
        int r = wm * 64 + mi * 16 + l15;
        af[mi] = *(const bf16x8*)(ab + r * 128 + (cb ^ ((r & 7) << 4)));
      }
      #pragma unroll
      for (int ni = 0; ni < 2; ++ni) {
        int r = wn * 32 + ni * 16 + l15;
        int o = r * 128 + (cb ^ ((r & 7) << 4));
        bgf[ni]  = *(const bf16x8*)(gb + o);
        buf2[ni] = *(const bf16x8*)(ub + o);
      }
      #pragma unroll
      for (int mi = 0; mi < 4; ++mi)
        #pragma unroll
        for (int ni = 0; ni < 2; ++ni) {
          accg[mi][ni] = __builtin_amdgcn_mfma_f32_16x16x32_bf16(af[mi], bgf[ni],  accg[mi][ni], 0, 0, 0);
          accu[mi][ni] = __builtin_amdgcn_mfma_f32_16x16x32_bf16(af[mi], buf2[ni], accu[mi][ni], 0, 0, 0);
        }
    }
  };

  constexpr int NK = H_ / G1_BK;   // 32
  // prologue
  stageA(0, 0); loadB(0); writeB(0);
  __syncthreads();
  int cur = 0;
  for (int kt = 0; kt < NK; ++kt) {
    if (kt + 1 < NK) { stageA(cur ^ 1, (kt + 1) * G1_BK); loadB((kt + 1) * G1_BK); }
    compute(cur);
    if (kt + 1 < NK) writeB(cur ^ 1);
    __syncthreads();             // drains gload_lds (vmcnt0) + ds_writes (lgkm); nxt ready
    cur ^= 1;
  }

  // epilogue: silu(g)*u -> bf16 h[slot][i]
  #pragma unroll
  for (int mi = 0; mi < 4; ++mi)
    #pragma unroll
    for (int ni = 0; ni < 2; ++ni)
      #pragma unroll
      for (int j = 0; j < 4; ++j) {
        int rel = wm*64 + mi*16 + l4*4 + j;
        if (m0 + rel < cnt) {
          int col = n0 + wn*32 + ni*16 + l15;
          float g = accg[mi][ni][j];
          float u = accu[mi][ni][j];
          float hvv = (g / (1.0f + __expf(-g))) * u;
          hout[(size_t)(off + m0 + rel) * I_ + col] = (bf16_t)hvv;
        }
      }
}

// ================= GEMM2: h x w2^T -> per-slot partial (f32) =================
constexpr int G2_BM = 128, G2_BN = 128, G2_BK = 64;

__global__ __launch_bounds__(256, 2)
void gemm2_kernel(const bf16_t* __restrict__ hbuf, const float* __restrict__ w2,
                  const int* __restrict__ offs, const int* __restrict__ counts,
                  float* __restrict__ dpart)
{
  const int bid = blockIdx.x;
  const int e   = bid & 7;
  const int idx = bid >> 3;          // 0..255 = 16 m x 16 n
  const int mt  = idx & 15;
  const int nt  = idx >> 4;

  const int cnt = counts[e];
  const int m0 = mt * G2_BM;
  if (m0 >= cnt) return;
  const int off = offs[e];
  const int n0 = nt * G2_BN;
  const float* W = w2 + (size_t)e * ((size_t)H_ * I_) + (size_t)n0 * I_;

  __shared__ bf16_t Al[2][G2_BM][G2_BK];   // 32 KB
  __shared__ bf16_t Bl[2][G2_BN][G2_BK];   // 32 KB

  const int tid = threadIdx.x;
  const int lane = tid & 63, wid = tid >> 6;
  const int wm = wid >> 1, wn = wid & 1;
  const int l15 = lane & 15, l4 = lane >> 4;

  const bf16_t* agp[4]; int aoff[4];
  #pragma unroll
  for (int i = 0; i < 4; ++i) {
    int q = wid * 4 + i;
    int row = q * 8 + (lane >> 3);
    int slot = off + m0 + row, mx = off + cnt - 1;
    if (slot > mx) slot = mx;
    agp[i]  = hbuf + (size_t)slot * I_ + ((lane & 7) ^ (lane >> 3)) * 8;
    aoff[i] = q * 1024;
  }
  // B: thread covers row=tid>>1 (128 rows), 32 f32 at cols 4*(tid&1)+8i
  const int brow = tid >> 1, bq = tid & 1;
  const float* bsrc = W + (size_t)brow * I_;
  int wby[8];
  #pragma unroll
  for (int i = 0; i < 8; ++i)
    wby[i] = brow * 128 + ((8 * bq + 16 * i) ^ ((brow & 7) << 4));

  float4 br[8];
  auto loadB = [&](int k0) {
    #pragma unroll
    for (int i = 0; i < 8; ++i) br[i] = *(const float4*)(bsrc + k0 + 4 * bq + 8 * i);
  };
  auto stageA = [&](int b, int k0) {
    char* base = (char*)&Al[b][0][0];
    #pragma unroll
    for (int i = 0; i < 4; ++i) gload16(agp[i] + k0, base + aoff[i]);
  };
  auto writeB = [&](int b) {
    char* bb = (char*)&Bl[b][0][0];
    #pragma unroll
    for (int i = 0; i < 8; ++i)
      *(bf16x4*)(bb + wby[i]) = cvt4(br[i]);
  };

  f32x4 acc[4][4];
  #pragma unroll
  for (int mi = 0; mi < 4; ++mi)
    #pragma unroll
    for (int ni = 0; ni < 4; ++ni) acc[mi][ni] = f32x4{0.f,0.f,0.f,0.f};

  auto compute = [&](int b) {
    const char* ab = (const char*)&Al[b][0][0];
    const char* bb = (const char*)&Bl[b][0][0];
    #pragma unroll
    for (int ks = 0; ks < 2; ++ks) {
      const int cb = ks * 64 + l4 * 16;
      bf16x8 af[4], bf[4];
      #pragma unroll
      for (int mi = 0; mi < 4; ++mi) {
        int r = wm * 64 + mi * 16 + l15;
        af[mi] = *(const bf16x8*)(ab + r * 128 + (cb ^ ((r & 7) << 4)));
      }
      #pragma unroll
      for (int ni = 0; ni < 4; ++ni) {
        int r = wn * 64 + ni * 16 + l15;
        bf[ni] = *(const bf16x8*)(bb + r * 128 + (cb ^ ((r & 7) << 4)));
      }
      #pragma unroll
      for (int mi = 0; mi < 4; ++mi)
        #pragma unroll
        for (int ni = 0; ni < 4; ++ni)
          acc[mi][ni] = __builtin_amdgcn_mfma_f32_16x16x32_bf16(af[mi], bf[ni], acc[mi][ni], 0, 0, 0);
    }
  };

  constexpr int NK = I_ / G2_BK;   // 88
  stageA(0, 0); loadB(0); writeB(0);
  __syncthreads();
  int cur = 0;
  for (int kt = 0; kt < NK; ++kt) {
    if (kt + 1 < NK) { stageA(cur ^ 1, (kt + 1) * G2_BK); loadB((kt + 1) * G2_BK); }
    compute(cur);
    if (kt + 1 < NK) writeB(cur ^ 1);
    __syncthreads();
    cur ^= 1;
  }

  #pragma unroll
  for (int mi = 0; mi < 4; ++mi)
    #pragma unroll
    for (int ni = 0; ni < 4; ++ni)
      #pragma unroll
      for (int j = 0; j < 4; ++j) {
        int rel = wm*64 + mi*16 + l4*4 + j;
        if (m0 + rel < cnt) {
          int col = n0 + wn*64 + ni*16 + l15;
          dpart[(size_t)(off + m0 + rel) * H_ + col] = acc[mi][ni][j];
        }
      }
}

// ================= combine: out[t] = w0*d[s0] + w1*d[s1] =================
__global__ __launch_bounds__(256)
void combine_kernel(const float* __restrict__ dpart, const int* __restrict__ sot,
                    const float* __restrict__ tkw, float* __restrict__ out)
{
  int idx = blockIdx.x * 256 + threadIdx.x;     // T*H/4 total
  int t = idx >> 9;                              // H/4 = 512
  int c = (idx & 511) * 4;
  float wA = tkw[2*t], wB = tkw[2*t+1];
  int sA = sot[2*t], sB = sot[2*t+1];
  float4 a = *(const float4*)(dpart + (size_t)sA * H_ + c);
  float4 b = *(const float4*)(dpart + (size_t)sB * H_ + c);
  float4 o;
  o.x = wA*a.x + wB*b.x; o.y = wA*a.y + wB*b.y;
  o.z = wA*a.z + wB*b.z; o.w = wA*a.w + wB*b.w;
  *(float4*)(out + (size_t)t * H_ + c) = o;
}

extern "C" void kernel_launch(void* const* d_in, const int* in_sizes, int n_in,
                              void* d_out, int out_size, void* d_ws, size_t ws_size,
                              hipStream_t stream) {
  const float* hs = (const float*)d_in[0];
  const float* gw = (const float*)d_in[1];
  const float* w1 = (const float*)d_in[2];
  const float* w2 = (const float*)d_in[3];
  float* out = (float*)d_out;
  char* ws = (char*)d_ws;

  bf16_t* hb    = (bf16_t*)(ws + OFF_HB);
  bf16_t* hout  = (bf16_t*)(ws + OFF_HOUT);
  float*  dpart = (float*) (ws + OFF_DPART);
  int*    tos   = (int*)   (ws + OFF_TOS);
  int*    sot   = (int*)   (ws + OFF_SOT);
  int*    tki   = (int*)   (ws + OFF_TKI);
  float*  tkw   = (float*) (ws + OFF_TKW);
  int*    cnt   = (int*)   (ws + OFF_CNT);
  int*    offp  = (int*)   (ws + OFF_OFFS);
  int*    curp  = (int*)   (ws + OFF_CUR);

  hipMemsetAsync(ws + OFF_CNT, 0, 64, stream);   // zero expert counts each call

  router_kernel<<<T_, 256, 0, stream>>>(hs, gw, tki, tkw, cnt, hb);
  scan_kernel<<<1, 256, 0, stream>>>(cnt, tki, offp, curp, tos, sot);
  gemm1_kernel<<<(T_ / G1_BM) * (I_ / G1_BN) * E_, 256, 0, stream>>>(hb, w1, tos, offp, cnt, hout);
  gemm2_kernel<<<(T_ / G2_BM) * (H_ / G2_BN) * E_, 256, 0, stream>>>(hout, w2, offp, cnt, dpart);
  combine_kernel<<<(T_ * H_ / 4) / 256, 256, 0, stream>>>(dpart, sot, tkw, out);
}